// Round 12
// baseline (407.122 us; speedup 1.0000x reference)
//
#include <hip/hip_runtime.h>
#include <math.h>

#define NROWS 500000
#define DIM 256
#define YDIM 50
#define NLAB 1000

#define XT 64
#define NTX ((NROWS + XT - 1) / XT)      // 7813 (last tile: 32 valid rows)
#define XBLOCKS 256
#define ASTRIDE 264                      // bf16 elems per A-tile row (padded)
#define ZC 51                            // z' cols: 50 proj + 1 gate-dot
#define XREPS 3                          // MEASUREMENT: run x-loop 3x (re-zeroed)

#define YT 128
#define NTY ((NROWS + YT - 1) / YT)      // 3907
#define YBLOCKS 256

typedef __attribute__((ext_vector_type(8))) short frag_ab;
typedef __attribute__((ext_vector_type(4))) float frag_cd;

__device__ __forceinline__ float b2f(unsigned short u) {
    return __uint_as_float(((unsigned)u) << 16);
}
__device__ __forceinline__ unsigned short f2b(float f) {   // RNE f32->bf16
    unsigned u = __float_as_uint(f);
    return (unsigned short)((u + 0x7fffu + ((u >> 16) & 1u)) >> 16);
}
// LDS-only barrier: does NOT drain vmcnt -> global prefetches stay in flight.
__device__ __forceinline__ void bar_lds() {
    asm volatile("s_waitcnt lgkmcnt(0)\n\ts_barrier" ::: "memory");
}

// ============ x stream: z' = x @ [w2|w1]; R9 structure + packed scatter =====
// 2 barriers/tile: bar1 = sA+slab ready; bar2 = zst ready. Scatter in its own
// region (R9 position — measured better than merged). Wave w owns labels
// (lbl&15)==w -> accz RMW race-free, no barrier needed after scatter.
__global__ __launch_bounds__(1024) void k_xstream(
    const float* __restrict__ x, const int* __restrict__ labels,
    const float* __restrict__ w1, const float* __restrict__ b1,
    const float* __restrict__ w2, unsigned short* __restrict__ zpart,
    float* __restrict__ out)
{
    __shared__ __align__(16) unsigned short sA[XT * ASTRIDE];   // 33,792 B
    __shared__ __align__(16) float zst[XT][52];                 // 13,312 B
    __shared__ __align__(16) unsigned short accz[NLAB * YDIM];  // 100,000 B
    __shared__ int slab[2][XT];                                 //    512 B

    const int tid = threadIdx.x, lane = tid & 63, wib = tid >> 6;
    const int bid = blockIdx.x;
    const int mh = wib >> 2, jt = wib & 3;

    if (bid == 0 && tid == 0) out[0] = 0.0f;

    // B fragments: W' columns = [w2 cols 0..49 | w1 as col 50 | zeros]
    frag_ab bfr[8];
    {
        const int n = 16 * jt + (lane & 15);
        #pragma unroll
        for (int s = 0; s < 8; ++s) {
            const int k0 = 32 * s + (lane >> 4) * 8;
            #pragma unroll
            for (int i = 0; i < 8; ++i) {
                const int kk = k0 + i;
                float v = 0.f;
                if (n < YDIM)       v = w2[kk * YDIM + n];
                else if (n == YDIM) v = w1[kk];
                bfr[s][i] = (short)f2b(v);
            }
        }
    }
    const float b1v = b1[0];

    auto PREF = [&](int t, float4* r) {
        #pragma unroll
        for (int k = 0; k < 4; ++k) {
            const int rg = t * XT + 4 * wib + k;
            r[k] = (rg < NROWS)
                 ? reinterpret_cast<const float4*>(x)[(size_t)rg * 64 + lane]
                 : make_float4(0.f, 0.f, 0.f, 0.f);
        }
    };
    auto LLAB = [&](int t) -> int {
        const int rg = t * XT + tid;
        return (tid < XT && rg < NROWS) ? labels[rg] : 0;
    };

    auto process = [&](int pft, float4* r, int& lb, int par) {
        // ---- phase 0: slab, pack x->bf16, refill prefetch, A-write ----
        if (tid < XT) slab[par][tid] = lb;
        uint2 pk[4];
        #pragma unroll
        for (int k = 0; k < 4; ++k) {
            pk[k].x = (unsigned)f2b(r[k].x) | ((unsigned)f2b(r[k].y) << 16);
            pk[k].y = (unsigned)f2b(r[k].z) | ((unsigned)f2b(r[k].w) << 16);
        }
        PREF(pft, r);                  // depth-2: loads stay in flight
        lb = LLAB(pft);                // labels travel with this reg set
        const int row = 4 * wib;
        #pragma unroll
        for (int k = 0; k < 4; ++k)
            *reinterpret_cast<uint2*>(&sA[(row + k) * ASTRIDE + lane * 4]) = pk[k];
        bar_lds();                     // bar1: sA + slab[par] ready

        // ---- phase 1: MFMA (gate col rides along), stage z'-tile ----
        frag_cd c = {0.f, 0.f, 0.f, 0.f};
        #pragma unroll
        for (int s = 0; s < 8; ++s) {
            frag_ab a = *reinterpret_cast<const frag_ab*>(
                &sA[(16 * mh + (lane & 15)) * ASTRIDE + 32 * s + (lane >> 4) * 8]);
            c = __builtin_amdgcn_mfma_f32_16x16x32_bf16(a, bfr[s], c, 0, 0, 0);
        }
        const int zr = 16 * mh + (lane >> 4) * 4;
        const int zc = 16 * jt + (lane & 15);
        if (zc < ZC) {
            zst[zr + 0][zc] = c[0]; zst[zr + 1][zc] = c[1];
            zst[zr + 2][zc] = c[2]; zst[zr + 3][zc] = c[3];
        }
        bar_lds();                     // bar2: zst ready

        // ---- phase 2: gated scatter, pair-packed RMW, own region ----
        {
            const int lbl_lane = slab[par][lane];
            unsigned long long mask = __ballot((lbl_lane & 15) == wib);
            while (mask) {
                const int r2 = __builtin_ctzll(mask);
                mask &= mask - 1;
                const int lbv = __shfl(lbl_lane, r2);
                const float d = zst[r2][YDIM];           // broadcast read
                const float g = 1.0f / (1.0f + __expf(-(d + b1v)));
                if (lane < 25) {
                    const float2 zv =
                        *reinterpret_cast<const float2*>(&zst[r2][2 * lane]);
                    unsigned* ap =
                        reinterpret_cast<unsigned*>(&accz[lbv * YDIM + 2 * lane]);
                    const unsigned old = *ap;
                    const float lo = b2f((unsigned short)(old & 0xffffu)) + g * zv.x;
                    const float hi = b2f((unsigned short)(old >> 16))     + g * zv.y;
                    *ap = (unsigned)f2b(lo) | ((unsigned)f2b(hi) << 16);
                }
            }
        }
        // zst/slab reuse protected by next tile's bar1 (lgkmcnt(0) drains reads)
    };

    // MEASUREMENT: repeat the full pass XREPS times (re-zero accz each rep).
    // Output identical to a single pass; dur_us/rocprof row isolates xstream.
    for (int rep = 0; rep < XREPS; ++rep) {
        __syncthreads();
        for (int k = tid; k < NLAB * YDIM / 2; k += 1024)
            reinterpret_cast<unsigned*>(accz)[k] = 0u;
        __syncthreads();

        float4 rA[4], rB[4];
        PREF(bid, rA);
        PREF(bid + XBLOCKS, rB);
        int lbA = LLAB(bid), lbB = LLAB(bid + XBLOCKS);
        int par = 0;
        for (int t = bid; t < NTX; t += 2 * XBLOCKS) {
            process(t + 2 * XBLOCKS, rA, lbA, par); par ^= 1;
            if (t + XBLOCKS < NTX) {
                process(t + 3 * XBLOCKS, rB, lbB, par); par ^= 1;
            }
        }
    }
    __syncthreads();
    unsigned short* zp = zpart + (size_t)bid * (NLAB * YDIM);
    for (int k = tid; k < NLAB * YDIM; k += 1024) zp[k] = accz[k];
}

// ============ y stream: ballot + pair-packed RMW scatter + counts ===========
__global__ __launch_bounds__(1024) void k_ystream(
    const float* __restrict__ y, const int* __restrict__ labels,
    unsigned short* __restrict__ ypart, int* __restrict__ gcnt)
{
    __shared__ __align__(16) unsigned short accy[NLAB * YDIM];  // 100,000 B
    __shared__ __align__(16) float yst[2][YT * YDIM];           //  51,200 B
    __shared__ int slab[2][YT];                                 //   1,024 B
    __shared__ int cnt[NLAB];                                   //   4,000 B

    const int tid = threadIdx.x, lane = tid & 63, wib = tid >> 6;
    const int bid = blockIdx.x;

    for (int k = tid; k < NLAB * YDIM / 2; k += 1024)
        reinterpret_cast<unsigned*>(accy)[k] = 0u;
    for (int k = tid; k < NLAB; k += 1024) cnt[k] = 0;
    __syncthreads();

    auto PREFY = [&](int t, float* v, int& myl) {
        const size_t base = (size_t)t * YT * YDIM;
        const int n = (t < NTY) ? (min(YT, NROWS - t * YT) * YDIM) : 0;
        #pragma unroll
        for (int i = 0; i < 7; ++i) {
            const int k = tid + i * 1024;
            v[i] = (k < n) ? y[base + k] : 0.f;
        }
        const int rg = t * YT + tid;
        myl = (tid < YT && t < NTY && rg < NROWS) ? labels[rg] : -1;
    };

    auto process = [&](int pft, float* v, int& myl, int par) {
        #pragma unroll
        for (int i = 0; i < 7; ++i) {
            const int k = tid + i * 1024;
            if (k < YT * YDIM) yst[par][k] = v[i];
        }
        if (tid < YT) {
            const bool valid = (myl >= 0);
            slab[par][tid] = valid ? myl : 0;
            if (valid) atomicAdd(&cnt[myl], 1);
        }
        PREFY(pft, v, myl);            // depth-2: loads stay in flight
        bar_lds();                     // yst[par] + slab[par] ready

        {
            const int l0 = slab[par][lane];
            const int l1 = slab[par][64 + lane];
            unsigned long long m0 = __ballot((l0 & 15) == wib);
            unsigned long long m1 = __ballot((l1 & 15) == wib);
            while (m0) {
                const int r = __builtin_ctzll(m0); m0 &= m0 - 1;
                const int lb = __shfl(l0, r);
                if (lane < 25) {
                    const float2 yv = *reinterpret_cast<const float2*>(
                        &yst[par][r * YDIM + 2 * lane]);
                    unsigned* ap =
                        reinterpret_cast<unsigned*>(&accy[lb * YDIM + 2 * lane]);
                    const unsigned old = *ap;
                    const float lo = b2f((unsigned short)(old & 0xffffu)) + yv.x;
                    const float hi = b2f((unsigned short)(old >> 16))     + yv.y;
                    *ap = (unsigned)f2b(lo) | ((unsigned)f2b(hi) << 16);
                }
            }
            while (m1) {
                const int r = __builtin_ctzll(m1); m1 &= m1 - 1;
                const int lb = __shfl(l1, r);
                if (lane < 25) {
                    const float2 yv = *reinterpret_cast<const float2*>(
                        &yst[par][(64 + r) * YDIM + 2 * lane]);
                    unsigned* ap =
                        reinterpret_cast<unsigned*>(&accy[lb * YDIM + 2 * lane]);
                    const unsigned old = *ap;
                    const float lo = b2f((unsigned short)(old & 0xffffu)) + yv.x;
                    const float hi = b2f((unsigned short)(old >> 16))     + yv.y;
                    *ap = (unsigned)f2b(lo) | ((unsigned)f2b(hi) << 16);
                }
            }
        }
        // next tile writes yst[par^1]; yst[par] rewrite is >=1 barrier away.
    };

    float vA[7], vB[7];
    int mA, mB;
    PREFY(bid, vA, mA);
    PREFY(bid + YBLOCKS, vB, mB);
    int par = 0;
    for (int t = bid; t < NTY; t += 2 * YBLOCKS) {
        process(t + 2 * YBLOCKS, vA, mA, par); par ^= 1;
        if (t + YBLOCKS < NTY) {
            process(t + 3 * YBLOCKS, vB, mB, par); par ^= 1;
        }
    }
    __syncthreads();
    unsigned short* yp = ypart + (size_t)bid * (NLAB * YDIM);
    for (int k = tid; k < NLAB * YDIM; k += 1024) yp[k] = accy[k];
    for (int k = tid; k < NLAB; k += 1024)
        if (cnt[k]) atomicAdd(&gcnt[k], cnt[k]);
}

// ============ finalize: coalesced partial-reduce + double softmax + loss ===
__global__ __launch_bounds__(256) void k_finalize(
    const unsigned short* __restrict__ zpart,
    const unsigned short* __restrict__ ypart,
    const int* __restrict__ gcnt,
    const float* __restrict__ b2, float* __restrict__ out)
{
    const int tid = threadIdx.x, lane = tid & 63, grp = tid >> 6;
    const int k0 = blockIdx.x * 200;

    float zs = 0.f, ys = 0.f;
    if (tid < 200) {
        const size_t idx = (size_t)k0 + tid;
        #pragma unroll 4
        for (int p = 0; p < XBLOCKS; ++p) {
            zs += b2f(zpart[(size_t)p * (NLAB * YDIM) + idx]);
            ys += b2f(ypart[(size_t)p * (NLAB * YDIM) + idx]);
        }
    }
    __shared__ float zl[200], yl[200];
    if (tid < 200) { zl[tid] = zs; yl[tid] = ys; }
    __syncthreads();

    const int l = blockIdx.x * 4 + grp;
    const bool act = lane < YDIM;
    const float zv = act ? zl[grp * 50 + lane] : 0.f;
    const float yv = act ? yl[grp * 50 + lane] : 0.f;

    const float denom = fmaxf((float)gcnt[l], 1.0f);
    const float NEG = -3.402823466e38f;
    float logit = act ? (zv / denom + b2[lane]) : NEG;
    const float ymean = act ? (yv / denom) : 0.f;

    float m = logit;
    #pragma unroll
    for (int o = 32; o > 0; o >>= 1) m = fmaxf(m, __shfl_xor(m, o));
    float e = act ? __expf(logit - m) : 0.f;
    float s = e;
    #pragma unroll
    for (int o = 32; o > 0; o >>= 1) s += __shfl_xor(s, o);
    const float p = e / s;                 // prediction

    float pm = act ? p : NEG;              // faithful double softmax
    float m2 = pm;
    #pragma unroll
    for (int o = 32; o > 0; o >>= 1) m2 = fmaxf(m2, __shfl_xor(m2, o));
    float e2 = act ? __expf(p - m2) : 0.f;
    float s2 = e2;
    #pragma unroll
    for (int o = 32; o > 0; o >>= 1) s2 += __shfl_xor(s2, o);
    const float logp = p - m2 - __logf(s2);

    float contrib = act ? ymean * logp : 0.f;
    #pragma unroll
    for (int o = 32; o > 0; o >>= 1) contrib += __shfl_xor(contrib, o);
    if (lane == 0) atomicAdd(out, -contrib / (float)NLAB);
}

extern "C" void kernel_launch(void* const* d_in, const int* in_sizes, int n_in,
                              void* d_out, int out_size, void* d_ws, size_t ws_size,
                              hipStream_t stream) {
    const float* x      = (const float*)d_in[0];
    const int*   labels = (const int*)  d_in[1];
    const float* y      = (const float*)d_in[2];
    const float* w1     = (const float*)d_in[3];
    const float* b1     = (const float*)d_in[4];
    const float* w2     = (const float*)d_in[5];
    const float* b2     = (const float*)d_in[6];
    float* out = (float*)d_out;

    // ws: gcnt[1024] ints | zpart[256][50000] bf16 | ypart[256][50000] bf16
    int* gcnt = (int*)d_ws;
    unsigned short* zpart = (unsigned short*)((char*)d_ws + 4096);
    unsigned short* ypart = (unsigned short*)((char*)d_ws + 4096 +
                             (size_t)XBLOCKS * NLAB * YDIM * 2);

    hipMemsetAsync(gcnt, 0, NLAB * sizeof(int), stream);
    k_xstream<<<XBLOCKS, 1024, 0, stream>>>(x, labels, w1, b1, w2, zpart, out);
    k_ystream<<<YBLOCKS, 1024, 0, stream>>>(y, labels, ypart, gcnt);
    k_finalize<<<250, 256, 0, stream>>>(zpart, ypart, gcnt, b2, out);
}

// Round 13
// 190.236 us; speedup vs baseline: 2.1401x; 2.1401x over previous
//
#include <hip/hip_runtime.h>
#include <math.h>

#define NROWS 500000
#define DIM 256
#define YDIM 50
#define NLAB 1000

#define XT 64
#define NTX ((NROWS + XT - 1) / XT)      // 7813 (last tile: 32 valid rows)
#define XBLOCKS 256
#define ASTRIDE 264                      // bf16 elems per A-tile row (padded)
#define ZC 51                            // z' cols: 50 proj + 1 gate-dot

#define YT 128
#define NTY ((NROWS + YT - 1) / YT)      // 3907
#define YBLOCKS 256

typedef __attribute__((ext_vector_type(8))) short frag_ab;
typedef __attribute__((ext_vector_type(4))) float frag_cd;

__device__ __forceinline__ float b2f(unsigned short u) {
    return __uint_as_float(((unsigned)u) << 16);
}
__device__ __forceinline__ unsigned short f2b(float f) {   // RNE f32->bf16
    unsigned u = __float_as_uint(f);
    return (unsigned short)((u + 0x7fffu + ((u >> 16) & 1u)) >> 16);
}
// 1-inst RNE pack: D[15:0]=bf16(lo), D[31:16]=bf16(hi)  (gfx950 V_CVT_PK_BF16_F32)
__device__ __forceinline__ unsigned cvt_pk_bf16(float lo, float hi) {
    unsigned r;
    asm("v_cvt_pk_bf16_f32 %0, %1, %2" : "=v"(r) : "v"(lo), "v"(hi));
    return r;
}
// LDS-only barrier: does NOT drain vmcnt -> global prefetches stay in flight.
__device__ __forceinline__ void bar_lds() {
    asm volatile("s_waitcnt lgkmcnt(0)\n\ts_barrier" ::: "memory");
}

// ============ x stream: z' = x @ [w2|w1]; gate post-MFMA; dual-half scatter ==
// 2 barriers/tile: bar1 = sA+slab ready; bar2 = zst ready.
// Wave w owns labels (lbl&15)==w -> accz RMW race-free (halves handle
// DIFFERENT labels concurrently -> different accz rows -> still race-free).
__global__ __launch_bounds__(1024) void k_xstream(
    const float* __restrict__ x, const int* __restrict__ labels,
    const float* __restrict__ w1, const float* __restrict__ b1,
    const float* __restrict__ w2, unsigned short* __restrict__ zpart,
    float* __restrict__ out)
{
    __shared__ __align__(16) unsigned short sA[XT * ASTRIDE];   // 33,792 B
    __shared__ __align__(16) float zst[XT][52];                 // 13,312 B
    __shared__ __align__(16) unsigned short accz[NLAB * YDIM];  // 100,000 B
    __shared__ int slab[2][XT];                                 //    512 B

    const int tid = threadIdx.x, lane = tid & 63, wib = tid >> 6;
    const int bid = blockIdx.x;
    const int mh = wib >> 2, jt = wib & 3;
    const int half = lane >> 5, li = lane & 31;

    if (bid == 0 && tid == 0) out[0] = 0.0f;
    for (int k = tid; k < NLAB * YDIM / 2; k += 1024)
        reinterpret_cast<unsigned*>(accz)[k] = 0u;

    // B fragments: W' columns = [w2 cols 0..49 | w1 as col 50 | zeros]
    frag_ab bfr[8];
    {
        const int n = 16 * jt + (lane & 15);
        #pragma unroll
        for (int s = 0; s < 8; ++s) {
            const int k0 = 32 * s + (lane >> 4) * 8;
            #pragma unroll
            for (int i = 0; i < 8; ++i) {
                const int kk = k0 + i;
                float v = 0.f;
                if (n < YDIM)       v = w2[kk * YDIM + n];
                else if (n == YDIM) v = w1[kk];
                bfr[s][i] = (short)f2b(v);
            }
        }
    }
    const float b1v = b1[0];
    __syncthreads();                                  // accz zeroed

    auto PREF = [&](int t, float4* r) {
        #pragma unroll
        for (int k = 0; k < 4; ++k) {
            const int rg = t * XT + 4 * wib + k;
            r[k] = (rg < NROWS)
                 ? reinterpret_cast<const float4*>(x)[(size_t)rg * 64 + lane]
                 : make_float4(0.f, 0.f, 0.f, 0.f);
        }
    };
    auto LLAB = [&](int t) -> int {
        const int rg = t * XT + tid;
        return (tid < XT && rg < NROWS) ? labels[rg] : 0;
    };

    auto process = [&](int pft, float4* r, int& lb, int par) {
        // ---- phase 0: slab, cvt_pk pack, refill prefetch, A-write ----
        if (tid < XT) slab[par][tid] = lb;
        uint2 pk[4];
        #pragma unroll
        for (int k = 0; k < 4; ++k) {
            pk[k].x = cvt_pk_bf16(r[k].x, r[k].y);
            pk[k].y = cvt_pk_bf16(r[k].z, r[k].w);
        }
        PREF(pft, r);                  // depth-2: loads stay in flight
        lb = LLAB(pft);                // labels travel with this reg set
        const int row = 4 * wib;
        #pragma unroll
        for (int k = 0; k < 4; ++k)
            *reinterpret_cast<uint2*>(&sA[(row + k) * ASTRIDE + lane * 4]) = pk[k];
        bar_lds();                     // bar1: sA + slab[par] ready

        // ---- phase 1: MFMA (gate col rides along), stage z'-tile ----
        frag_cd c = {0.f, 0.f, 0.f, 0.f};
        #pragma unroll
        for (int s = 0; s < 8; ++s) {
            frag_ab a = *reinterpret_cast<const frag_ab*>(
                &sA[(16 * mh + (lane & 15)) * ASTRIDE + 32 * s + (lane >> 4) * 8]);
            c = __builtin_amdgcn_mfma_f32_16x16x32_bf16(a, bfr[s], c, 0, 0, 0);
        }
        const int zr = 16 * mh + (lane >> 4) * 4;
        const int zc = 16 * jt + (lane & 15);
        if (zc < ZC) {
            zst[zr + 0][zc] = c[0]; zst[zr + 1][zc] = c[1];
            zst[zr + 2][zc] = c[2]; zst[zr + 3][zc] = c[3];
        }
        bar_lds();                     // bar2: zst ready

        // ---- phase 2: gated dual-half scatter (2 rows per step) ----
        {
            const int lbl_lane = slab[par][lane];
            unsigned long long mask = __ballot((lbl_lane & 15) == wib);
            while (mask) {
                const int ra = __builtin_ctzll(mask);
                mask &= mask - 1;
                int rb = -1;
                if (mask) { rb = __builtin_ctzll(mask); mask &= mask - 1; }
                const int r2 = (half && rb >= 0) ? rb : ra;
                const int lbv = __shfl(lbl_lane, r2);     // full-wave participation
                const float d = zst[r2][YDIM];            // broadcast-ish read
                const bool act = (half == 0) || (rb >= 0);
                if (act && li < 25) {
                    const float g = 1.0f / (1.0f + __expf(-(d + b1v)));
                    const float2 zv =
                        *reinterpret_cast<const float2*>(&zst[r2][2 * li]);
                    unsigned* ap =
                        reinterpret_cast<unsigned*>(&accz[lbv * YDIM + 2 * li]);
                    const unsigned old = *ap;
                    const float lo = b2f((unsigned short)(old & 0xffffu)) + g * zv.x;
                    const float hi = b2f((unsigned short)(old >> 16))     + g * zv.y;
                    *ap = cvt_pk_bf16(lo, hi);
                }
            }
        }
        // zst/slab reuse protected by next tile's bar1 (lgkmcnt(0) drains reads)
    };

    float4 rA[4], rB[4];
    PREF(bid, rA);
    PREF(bid + XBLOCKS, rB);
    int lbA = LLAB(bid), lbB = LLAB(bid + XBLOCKS);
    int par = 0;
    for (int t = bid; t < NTX; t += 2 * XBLOCKS) {
        process(t + 2 * XBLOCKS, rA, lbA, par); par ^= 1;
        if (t + XBLOCKS < NTX) {
            process(t + 3 * XBLOCKS, rB, lbB, par); par ^= 1;
        }
    }
    __syncthreads();
    unsigned short* zp = zpart + (size_t)bid * (NLAB * YDIM);
    for (int k = tid; k < NLAB * YDIM; k += 1024) zp[k] = accz[k];
}

// ============ y stream: dual-half scatter + counts ============
__global__ __launch_bounds__(1024) void k_ystream(
    const float* __restrict__ y, const int* __restrict__ labels,
    unsigned short* __restrict__ ypart, int* __restrict__ gcnt)
{
    __shared__ __align__(16) unsigned short accy[NLAB * YDIM];  // 100,000 B
    __shared__ __align__(16) float yst[2][YT * YDIM];           //  51,200 B
    __shared__ int slab[2][YT];                                 //   1,024 B
    __shared__ int cnt[NLAB];                                   //   4,000 B

    const int tid = threadIdx.x, lane = tid & 63, wib = tid >> 6;
    const int bid = blockIdx.x;
    const int half = lane >> 5, li = lane & 31;

    for (int k = tid; k < NLAB * YDIM / 2; k += 1024)
        reinterpret_cast<unsigned*>(accy)[k] = 0u;
    for (int k = tid; k < NLAB; k += 1024) cnt[k] = 0;
    __syncthreads();

    auto PREFY = [&](int t, float* v, int& myl) {
        const size_t base = (size_t)t * YT * YDIM;
        const int n = (t < NTY) ? (min(YT, NROWS - t * YT) * YDIM) : 0;
        #pragma unroll
        for (int i = 0; i < 7; ++i) {
            const int k = tid + i * 1024;
            v[i] = (k < n) ? y[base + k] : 0.f;
        }
        const int rg = t * YT + tid;
        myl = (tid < YT && t < NTY && rg < NROWS) ? labels[rg] : -1;
    };

    // dual-half scatter over one 64-row mask group (row offset ro)
    auto SCAT = [&](unsigned long long mask, int lblv, int ro, int par) {
        while (mask) {
            const int ra = __builtin_ctzll(mask);
            mask &= mask - 1;
            int rb = -1;
            if (mask) { rb = __builtin_ctzll(mask); mask &= mask - 1; }
            const int r2 = (half && rb >= 0) ? rb : ra;
            const int lb = __shfl(lblv, r2);
            const bool act = (half == 0) || (rb >= 0);
            if (act && li < 25) {
                const float2 yv = *reinterpret_cast<const float2*>(
                    &yst[par][(ro + r2) * YDIM + 2 * li]);
                unsigned* ap =
                    reinterpret_cast<unsigned*>(&accy[lb * YDIM + 2 * li]);
                const unsigned old = *ap;
                const float lo = b2f((unsigned short)(old & 0xffffu)) + yv.x;
                const float hi = b2f((unsigned short)(old >> 16))     + yv.y;
                *ap = cvt_pk_bf16(lo, hi);
            }
        }
    };

    auto process = [&](int pft, float* v, int& myl, int par) {
        #pragma unroll
        for (int i = 0; i < 7; ++i) {
            const int k = tid + i * 1024;
            if (k < YT * YDIM) yst[par][k] = v[i];
        }
        if (tid < YT) {
            const bool valid = (myl >= 0);
            slab[par][tid] = valid ? myl : 0;
            if (valid) atomicAdd(&cnt[myl], 1);
        }
        PREFY(pft, v, myl);            // depth-2: loads stay in flight
        bar_lds();                     // yst[par] + slab[par] ready

        const int l0 = slab[par][lane];
        const int l1 = slab[par][64 + lane];
        SCAT(__ballot((l0 & 15) == wib), l0, 0,  par);
        SCAT(__ballot((l1 & 15) == wib), l1, 64, par);
        // next tile writes yst[par^1]; yst[par] rewrite is >=1 barrier away.
    };

    float vA[7], vB[7];
    int mA, mB;
    PREFY(bid, vA, mA);
    PREFY(bid + YBLOCKS, vB, mB);
    int par = 0;
    for (int t = bid; t < NTY; t += 2 * YBLOCKS) {
        process(t + 2 * YBLOCKS, vA, mA, par); par ^= 1;
        if (t + YBLOCKS < NTY) {
            process(t + 3 * YBLOCKS, vB, mB, par); par ^= 1;
        }
    }
    __syncthreads();
    unsigned short* yp = ypart + (size_t)bid * (NLAB * YDIM);
    for (int k = tid; k < NLAB * YDIM; k += 1024) yp[k] = accy[k];
    for (int k = tid; k < NLAB; k += 1024)
        if (cnt[k]) atomicAdd(&gcnt[k], cnt[k]);
}

// ============ finalize: coalesced partial-reduce + double softmax + loss ===
__global__ __launch_bounds__(256) void k_finalize(
    const unsigned short* __restrict__ zpart,
    const unsigned short* __restrict__ ypart,
    const int* __restrict__ gcnt,
    const float* __restrict__ b2, float* __restrict__ out)
{
    const int tid = threadIdx.x, lane = tid & 63, grp = tid >> 6;
    const int k0 = blockIdx.x * 200;

    float zs = 0.f, ys = 0.f;
    if (tid < 200) {
        const size_t idx = (size_t)k0 + tid;
        #pragma unroll 4
        for (int p = 0; p < XBLOCKS; ++p) {
            zs += b2f(zpart[(size_t)p * (NLAB * YDIM) + idx]);
            ys += b2f(ypart[(size_t)p * (NLAB * YDIM) + idx]);
        }
    }
    __shared__ float zl[200], yl[200];
    if (tid < 200) { zl[tid] = zs; yl[tid] = ys; }
    __syncthreads();

    const int l = blockIdx.x * 4 + grp;
    const bool act = lane < YDIM;
    const float zv = act ? zl[grp * 50 + lane] : 0.f;
    const float yv = act ? yl[grp * 50 + lane] : 0.f;

    const float denom = fmaxf((float)gcnt[l], 1.0f);
    const float NEG = -3.402823466e38f;
    float logit = act ? (zv / denom + b2[lane]) : NEG;
    const float ymean = act ? (yv / denom) : 0.f;

    float m = logit;
    #pragma unroll
    for (int o = 32; o > 0; o >>= 1) m = fmaxf(m, __shfl_xor(m, o));
    float e = act ? __expf(logit - m) : 0.f;
    float s = e;
    #pragma unroll
    for (int o = 32; o > 0; o >>= 1) s += __shfl_xor(s, o);
    const float p = e / s;                 // prediction

    float pm = act ? p : NEG;              // faithful double softmax
    float m2 = pm;
    #pragma unroll
    for (int o = 32; o > 0; o >>= 1) m2 = fmaxf(m2, __shfl_xor(m2, o));
    float e2 = act ? __expf(p - m2) : 0.f;
    float s2 = e2;
    #pragma unroll
    for (int o = 32; o > 0; o >>= 1) s2 += __shfl_xor(s2, o);
    const float logp = p - m2 - __logf(s2);

    float contrib = act ? ymean * logp : 0.f;
    #pragma unroll
    for (int o = 32; o > 0; o >>= 1) contrib += __shfl_xor(contrib, o);
    if (lane == 0) atomicAdd(out, -contrib / (float)NLAB);
}

extern "C" void kernel_launch(void* const* d_in, const int* in_sizes, int n_in,
                              void* d_out, int out_size, void* d_ws, size_t ws_size,
                              hipStream_t stream) {
    const float* x      = (const float*)d_in[0];
    const int*   labels = (const int*)  d_in[1];
    const float* y      = (const float*)d_in[2];
    const float* w1     = (const float*)d_in[3];
    const float* b1     = (const float*)d_in[4];
    const float* w2     = (const float*)d_in[5];
    const float* b2     = (const float*)d_in[6];
    float* out = (float*)d_out;

    // ws: gcnt[1024] ints | zpart[256][50000] bf16 | ypart[256][50000] bf16
    int* gcnt = (int*)d_ws;
    unsigned short* zpart = (unsigned short*)((char*)d_ws + 4096);
    unsigned short* ypart = (unsigned short*)((char*)d_ws + 4096 +
                             (size_t)XBLOCKS * NLAB * YDIM * 2);

    hipMemsetAsync(gcnt, 0, NLAB * sizeof(int), stream);
    k_xstream<<<XBLOCKS, 1024, 0, stream>>>(x, labels, w1, b1, w2, zpart, out);
    k_ystream<<<YBLOCKS, 1024, 0, stream>>>(y, labels, ypart, gcnt);
    k_finalize<<<250, 256, 0, stream>>>(zpart, ypart, gcnt, b2, out);
}